// Round 1
// baseline (698.270 us; speedup 1.0000x reference)
//
#include <hip/hip_runtime.h>

namespace {

constexpr int Hh = 192, Ww = 192, Cc = 16, Oo = 64, Bb = 4;
constexpr int TH = 4, TW = 32, NT = 128;   // 4x32 pixel tile, 128 threads (2 waves)
constexpr int ER  = TH + 22;               // 26 extended rows  (di in [-11,11])
constexpr int ECU = TW + 42;               // 74 extended cols  (dj in [-21,21])
constexpr int EC  = 76;                    // padded LDS stride (16B aligned)

// Each feature = (vertical segment sum) + (horizontal segment sum), scaled by 1/n.
// V(vdj, vi0, vi1): rows h+vi0..h+vi1 at col w+vdj ; H(hdi, hj0, hj1): cols w+hj0..w+hj1 at row h+hdi.
struct FD { int hasV; int vdj, vi0, vi1; int hasH; int hdi, hj0, hj1; float inv_n; };

constexpr FD FT[49] = {
    // 9 inner taps (i,j) in row-major order, n=1
    {1,-1,-1,-1, 0,0,0,0, 1.f}, {1, 0,-1,-1, 0,0,0,0, 1.f}, {1, 1,-1,-1, 0,0,0,0, 1.f},
    {1,-1, 0, 0, 0,0,0,0, 1.f}, {1, 0, 0, 0, 0,0,0,0, 1.f}, {1, 1, 0, 0, 0,0,0,0, 1.f},
    {1,-1, 1, 1, 0,0,0,0, 1.f}, {1, 0, 1, 1, 0,0,0,0, 1.f}, {1, 1, 1, 1, 0,0,0,0, 1.f},
    // ring5 (16): i=-2 row
    {1,-2,-2, 2, 1,-2,-1, 2, 1.f/9.f},   // (-2,-2)
    {1,-1,-2, 2, 0,0,0,0, 0.2f},         // (-2,-1)
    {1, 0,-2, 2, 0,0,0,0, 0.2f},         // (-2, 0)
    {1, 1,-2, 2, 0,0,0,0, 0.2f},         // (-2, 1)
    {1, 2,-2, 2, 1,-2,-2, 1, 1.f/9.f},   // (-2, 2)
    {0,0,0,0, 1,-1,-2, 2, 0.2f},         // (-1,-2)
    {0,0,0,0, 1,-1,-2, 2, 0.2f},         // (-1, 2)
    {0,0,0,0, 1, 0,-2, 2, 0.2f},         // ( 0,-2)
    {0,0,0,0, 1, 0,-2, 2, 0.2f},         // ( 0, 2)
    {0,0,0,0, 1, 1,-2, 2, 0.2f},         // ( 1,-2)
    {0,0,0,0, 1, 1,-2, 2, 0.2f},         // ( 1, 2)
    {1,-2,-2, 2, 1, 2,-1, 2, 1.f/9.f},   // ( 2,-2)
    {1,-1,-2, 2, 0,0,0,0, 0.2f},         // ( 2,-1)
    {1, 0,-2, 2, 0,0,0,0, 0.2f},         // ( 2, 0)
    {1, 1,-2, 2, 0,0,0,0, 0.2f},         // ( 2, 1)
    {1, 2,-2, 2, 1, 2,-2, 1, 1.f/9.f},   // ( 2, 2)
    // ring7 (24): i=-3 row
    {1,-3,-3,11, 1,-3,-2,21, 1.f/39.f},  // (-3,-3)
    {1,-2,-3,11, 0,0,0,0, 1.f/15.f},     // (-3,-2)
    {1,-1,-3,11, 0,0,0,0, 1.f/15.f},     // (-3,-1)
    {1, 0,-3,11, 0,0,0,0, 1.f/15.f},     // (-3, 0)
    {1, 1,-3,11, 0,0,0,0, 1.f/15.f},     // (-3, 1)
    {1, 2,-3,11, 0,0,0,0, 1.f/15.f},     // (-3, 2)
    {1, 3,-3,11, 1,-3,-21, 2, 1.f/39.f}, // (-3, 3)
    {0,0,0,0, 1,-2,-3,21, 0.04f},        // (-2,-3)
    {0,0,0,0, 1,-2,-21,3, 0.04f},        // (-2, 3)
    {0,0,0,0, 1,-1,-3,21, 0.04f},        // (-1,-3)
    {0,0,0,0, 1,-1,-21,3, 0.04f},        // (-1, 3)
    {0,0,0,0, 1, 0,-3,21, 0.04f},        // ( 0,-3)
    {0,0,0,0, 1, 0,-21,3, 0.04f},        // ( 0, 3)
    {0,0,0,0, 1, 1,-3,21, 0.04f},        // ( 1,-3)
    {0,0,0,0, 1, 1,-21,3, 0.04f},        // ( 1, 3)
    {0,0,0,0, 1, 2,-3,21, 0.04f},        // ( 2,-3)
    {0,0,0,0, 1, 2,-21,3, 0.04f},        // ( 2, 3)
    {1,-3,-11,3, 1, 3,-2,21, 1.f/39.f},  // ( 3,-3)
    {1,-2,-11,3, 0,0,0,0, 1.f/15.f},     // ( 3,-2)
    {1,-1,-11,3, 0,0,0,0, 1.f/15.f},     // ( 3,-1)
    {1, 0,-11,3, 0,0,0,0, 1.f/15.f},     // ( 3, 0)
    {1, 1,-11,3, 0,0,0,0, 1.f/15.f},     // ( 3, 1)
    {1, 2,-11,3, 0,0,0,0, 1.f/15.f},     // ( 3, 2)
    {1, 3,-11,3, 1, 3,-21,2, 1.f/39.f},  // ( 3, 3)
};

// Reproduces x-index of clip(h+3+u', 0, 197) into reflect-pad(3) of length-192 axis,
// where u = h + offset. Valid for u in [-21, 212].
__device__ __forceinline__ int mapIdx(int u) {
    if (u < 0) { u = -u; if (u > 3) u = 3; }
    else if (u > 191) { u = 382 - u; if (u < 188) u = 188; }
    return u;
}

__global__ __launch_bounds__(NT, 4)
void fova_fused(const float* __restrict__ x, const float* __restrict__ wgt,
                const float* __restrict__ bias, float* __restrict__ out)
{
    __shared__ float E [ER][EC];       // extended x tile (reflect+clip baked in)
    __shared__ float PV[ER + 1][EC];   // column prefix sums (row 0 = 0)
    __shared__ float PH[ER][EC];       // row prefix sums    (col 0 = 0), cols 0..74 used
    __shared__ float WL[32][52];       // weight slice for this c and o-half (49 used)

    const int tid = threadIdx.x;
    const int w0  = blockIdx.x * TW;
    const int h0  = blockIdx.y * TH;
    const int b   = blockIdx.z >> 1;
    const int oh  = blockIdx.z & 1;    // which half of O this block computes
    const int ph  = tid >> 5;          // 0..3
    const int pw  = tid & 31;          // 0..31
    const int ur  = ph + 11;           // pixel row in extended coords
    const int vcc = pw + 21;           // pixel col in extended coords

    float acc[32];
#pragma unroll
    for (int o = 0; o < 32; ++o) acc[o] = 0.f;

    for (int c = 0; c < Cc; ++c) {
        const float* xp = x + (size_t)(b * Cc + c) * Hh * Ww;
        // --- stage extended tile into LDS (coalesced along vv) ---
        for (int idx = tid; idx < ER * ECU; idx += NT) {
            int uu = idx / ECU;
            int vv = idx - uu * ECU;
            int gh = mapIdx(h0 + uu - 11);
            int gw = mapIdx(w0 + vv - 21);
            E[uu][vv] = xp[gh * Ww + gw];
        }
        // --- stage this c's weight slice (rows contiguous, k = c*49+f) ---
        const float* wrow = wgt + (size_t)(oh * 32) * 784 + c * 49;
        for (int idx = tid; idx < 32 * 49; idx += NT) {
            int o = idx / 49;
            int f = idx - o * 49;
            WL[o][f] = wrow[o * 784 + f];
        }
        __syncthreads();
        // --- column prefixes: only cols 18..55 are read by features ---
        if (tid < 38) {
            int col = 18 + tid;
            float r = 0.f;
            PV[0][col] = 0.f;
#pragma unroll
            for (int rr = 0; rr < ER; ++rr) { r += E[rr][col]; PV[rr + 1][col] = r; }
        }
        // --- row prefixes: only rows 8..17 are read by features ---
        if (tid >= 96 && tid < 106) {
            int row = 8 + (tid - 96);
            float r = 0.f;
            PH[row][0] = 0.f;
            for (int s = 0; s < ECU; ++s) { r += E[row][s]; PH[row][s + 1] = r; }
        }
        __syncthreads();

        // --- 49 features for this lane's pixel, all in registers ---
        float feat[49];
#pragma unroll
        for (int f = 0; f < 49; ++f) {
            float s = 0.f;
            if (FT[f].hasV) {
                int col = vcc + FT[f].vdj;
                s += PV[ur + FT[f].vi1 + 1][col] - PV[ur + FT[f].vi0][col];
            }
            if (FT[f].hasH) {
                int row = ur + FT[f].hdi;
                s += PH[row][vcc + FT[f].hj1 + 1] - PH[row][vcc + FT[f].hj0];
            }
            feat[f] = s * FT[f].inv_n;
        }

        // --- contraction: acc[o] += w[o, c*49+f] * feat[f] (weights broadcast from LDS) ---
#pragma unroll
        for (int o = 0; o < 32; ++o) {
            float a = acc[o];
#pragma unroll
            for (int f4 = 0; f4 < 48; f4 += 4) {
                float4 wv = *(const float4*)(&WL[o][f4]);
                a = fmaf(wv.x, feat[f4 + 0], a);
                a = fmaf(wv.y, feat[f4 + 1], a);
                a = fmaf(wv.z, feat[f4 + 2], a);
                a = fmaf(wv.w, feat[f4 + 3], a);
            }
            a = fmaf(WL[o][48], feat[48], a);
            acc[o] = a;
        }
        __syncthreads();   // before next c overwrites E/WL
    }

    const int h = h0 + ph, w = w0 + pw;
#pragma unroll
    for (int o = 0; o < 32; ++o) {
        int og = oh * 32 + o;
        out[(((size_t)b * Oo + og) * Hh + h) * Ww + w] = acc[o] + bias[og];
    }
}

} // namespace

extern "C" void kernel_launch(void* const* d_in, const int* in_sizes, int n_in,
                              void* d_out, int out_size, void* d_ws, size_t ws_size,
                              hipStream_t stream) {
    (void)in_sizes; (void)n_in; (void)d_ws; (void)ws_size; (void)out_size;
    const float* x    = (const float*)d_in[0];
    const float* wgt  = (const float*)d_in[1];
    const float* bias = (const float*)d_in[2];
    float* out        = (float*)d_out;

    dim3 grid(Ww / TW, Hh / TH, Bb * 2);   // 6 x 48 x 8 = 2304 blocks
    dim3 block(NT);
    fova_fused<<<grid, block, 0, stream>>>(x, wgt, bias, out);
}

// Round 5
// 297.326 us; speedup vs baseline: 2.3485x; 2.3485x over previous
//
#include <hip/hip_runtime.h>

typedef __attribute__((ext_vector_type(8))) short short8v;   // bf16x8 fragment
typedef __attribute__((ext_vector_type(4))) float float4v;   // fp32x4 accum
typedef unsigned short ushort;
typedef unsigned int uint;

namespace {

constexpr int Hh = 192, Ww = 192, Cc = 16, Oo = 64, Bb = 4;
constexpr int TH = 4, TW = 32, NT = 128;     // 4x32 pixel tile, 128 threads (2 waves)

// Each feature = (vertical segment sum) + (horizontal segment sum), scaled by 1/n.
struct FD { int hasV; int vdj, vi0, vi1; int hasH; int hdi, hj0, hj1; float inv_n; };

constexpr FD FT[49] = {
    // 9 inner taps (i,j) row-major, n=1
    {1,-1,-1,-1, 0,0,0,0, 1.f}, {1, 0,-1,-1, 0,0,0,0, 1.f}, {1, 1,-1,-1, 0,0,0,0, 1.f},
    {1,-1, 0, 0, 0,0,0,0, 1.f}, {1, 0, 0, 0, 0,0,0,0, 1.f}, {1, 1, 0, 0, 0,0,0,0, 1.f},
    {1,-1, 1, 1, 0,0,0,0, 1.f}, {1, 0, 1, 1, 0,0,0,0, 1.f}, {1, 1, 1, 1, 0,0,0,0, 1.f},
    // ring5 (16)
    {1,-2,-2, 2, 1,-2,-1, 2, 1.f/9.f},
    {1,-1,-2, 2, 0,0,0,0, 0.2f},
    {1, 0,-2, 2, 0,0,0,0, 0.2f},
    {1, 1,-2, 2, 0,0,0,0, 0.2f},
    {1, 2,-2, 2, 1,-2,-2, 1, 1.f/9.f},
    {0,0,0,0, 1,-1,-2, 2, 0.2f},
    {0,0,0,0, 1,-1,-2, 2, 0.2f},
    {0,0,0,0, 1, 0,-2, 2, 0.2f},
    {0,0,0,0, 1, 0,-2, 2, 0.2f},
    {0,0,0,0, 1, 1,-2, 2, 0.2f},
    {0,0,0,0, 1, 1,-2, 2, 0.2f},
    {1,-2,-2, 2, 1, 2,-1, 2, 1.f/9.f},
    {1,-1,-2, 2, 0,0,0,0, 0.2f},
    {1, 0,-2, 2, 0,0,0,0, 0.2f},
    {1, 1,-2, 2, 0,0,0,0, 0.2f},
    {1, 2,-2, 2, 1, 2,-2, 1, 1.f/9.f},
    // ring7 (24)
    {1,-3,-3,11, 1,-3,-2,21, 1.f/39.f},
    {1,-2,-3,11, 0,0,0,0, 1.f/15.f},
    {1,-1,-3,11, 0,0,0,0, 1.f/15.f},
    {1, 0,-3,11, 0,0,0,0, 1.f/15.f},
    {1, 1,-3,11, 0,0,0,0, 1.f/15.f},
    {1, 2,-3,11, 0,0,0,0, 1.f/15.f},
    {1, 3,-3,11, 1,-3,-21, 2, 1.f/39.f},
    {0,0,0,0, 1,-2,-3,21, 0.04f},
    {0,0,0,0, 1,-2,-21,3, 0.04f},
    {0,0,0,0, 1,-1,-3,21, 0.04f},
    {0,0,0,0, 1,-1,-21,3, 0.04f},
    {0,0,0,0, 1, 0,-3,21, 0.04f},
    {0,0,0,0, 1, 0,-21,3, 0.04f},
    {0,0,0,0, 1, 1,-3,21, 0.04f},
    {0,0,0,0, 1, 1,-21,3, 0.04f},
    {0,0,0,0, 1, 2,-3,21, 0.04f},
    {0,0,0,0, 1, 2,-21,3, 0.04f},
    {1,-3,-11,3, 1, 3,-2,21, 1.f/39.f},
    {1,-2,-11,3, 0,0,0,0, 1.f/15.f},
    {1,-1,-11,3, 0,0,0,0, 1.f/15.f},
    {1, 0,-11,3, 0,0,0,0, 1.f/15.f},
    {1, 1,-11,3, 0,0,0,0, 1.f/15.f},
    {1, 2,-11,3, 0,0,0,0, 1.f/15.f},
    {1, 3,-11,3, 1, 3,-21,2, 1.f/39.f},
};

// reflect-pad(3) + clip index map; valid for u in [-21, 212]
__device__ __forceinline__ int mapIdx(int u) {
    if (u < 0) { u = -u; if (u > 3) u = 3; }
    else if (u > 191) { u = 382 - u; if (u < 188) u = 188; }
    return u;
}

__device__ __forceinline__ ushort f2bf(float f) {   // RNE fp32->bf16 bits
    uint u = __builtin_bit_cast(uint, f);
    u += 0x7FFFu + ((u >> 16) & 1u);
    return (ushort)(u >> 16);
}

__global__ __launch_bounds__(NT, 2)
void fova_v5(const float* __restrict__ x, const float* __restrict__ wgt,
             const float* __restrict__ bias, float* __restrict__ out)
{
    __shared__ float  E [26][76];      // extended x tile (R1-verbatim geometry)
    __shared__ float  PV[27][76];      // column prefixes, absolute cols 18..55 used
    __shared__ float  PH[26][76];      // row prefixes, absolute rows 8..17 used
    __shared__ ushort featB[NT][66];   // bf16 feat bits [pixel][k], padded stride (66)

    const int tid  = threadIdx.x;
    const int lane = tid & 63;
    const int wv   = tid >> 6;          // wave id 0/1
    const int w0   = blockIdx.x * TW;
    const int h0   = blockIdx.y * TH;
    const int b    = blockIdx.z;
    const int ph   = tid >> 5;          // pixel row 0..3 (tid == pixel id)
    const int pw   = tid & 31;
    const int ur   = ph + 11;           // pixel row in extended coords
    const int vcc  = pw + 21;           // pixel col in extended coords

    float4v acc[4][4];
#pragma unroll
    for (int i = 0; i < 4; ++i)
#pragma unroll
        for (int j = 0; j < 4; ++j) acc[i][j] = (float4v)(0.f);

    for (int c = 0; c < Cc; ++c) {
        // ---- phase 1: stage E(c) (R1-verbatim) ----
        {
            const float* xp = x + (size_t)(b * Cc + c) * Hh * Ww;
            for (int idx = tid; idx < 26 * 74; idx += NT) {
                int uu = idx / 74, vvv = idx - uu * 74;
                E[uu][vvv] = xp[mapIdx(h0 + uu - 11) * Ww + mapIdx(w0 + vvv - 21)];
            }
        }
        __syncthreads();

        // ---- phase 2: serial prefix scans (R1-verbatim) ----
        if (tid < 38) {
            int col = 18 + tid;
            float r = 0.f;
            PV[0][col] = 0.f;
#pragma unroll
            for (int rr = 0; rr < 26; ++rr) { r += E[rr][col]; PV[rr + 1][col] = r; }
        }
        if (tid >= 96 && tid < 106) {
            int row = 8 + (tid - 96);
            float r = 0.f;
            PH[row][0] = 0.f;
            for (int s = 0; s < 74; ++s) { r += E[row][s]; PH[row][s + 1] = r; }
        }
        __syncthreads();

        // ---- phase 3: features (R1-verbatim) -> scalar bf16 stores ----
        {
            float feat[49];
#pragma unroll
            for (int f = 0; f < 49; ++f) {
                float s = 0.f;
                if (FT[f].hasV) {
                    int col = vcc + FT[f].vdj;
                    s += PV[ur + FT[f].vi1 + 1][col] - PV[ur + FT[f].vi0][col];
                }
                if (FT[f].hasH) {
                    int row = ur + FT[f].hdi;
                    s += PH[row][vcc + FT[f].hj1 + 1] - PH[row][vcc + FT[f].hj0];
                }
                feat[f] = s * FT[f].inv_n;
            }
#pragma unroll
            for (int f = 0; f < 49; ++f) featB[tid][f] = f2bf(feat[f]);
#pragma unroll
            for (int f = 49; f < 64; ++f) featB[tid][f] = 0;
        }
        __syncthreads();

        // ---- phase 4: contraction via MFMA; operands built from scalars ----
        {
            const float* wc = wgt + c * 49;
            const int olo = lane & 15, kg = lane >> 4;
#pragma unroll
            for (int kc = 0; kc < 2; ++kc) {
                const int k0 = kc * 32 + kg * 8;
                short8v afr[4];
#pragma unroll
                for (int ob = 0; ob < 4; ++ob) {
                    const int o = ob * 16 + olo;
                    uint4 u;
                    {
                        uint p0, p1, p2, p3;
                        ushort e0 = (k0 + 0 < 49) ? f2bf(wc[o * 784 + k0 + 0]) : (ushort)0;
                        ushort e1 = (k0 + 1 < 49) ? f2bf(wc[o * 784 + k0 + 1]) : (ushort)0;
                        ushort e2 = (k0 + 2 < 49) ? f2bf(wc[o * 784 + k0 + 2]) : (ushort)0;
                        ushort e3 = (k0 + 3 < 49) ? f2bf(wc[o * 784 + k0 + 3]) : (ushort)0;
                        ushort e4 = (k0 + 4 < 49) ? f2bf(wc[o * 784 + k0 + 4]) : (ushort)0;
                        ushort e5 = (k0 + 5 < 49) ? f2bf(wc[o * 784 + k0 + 5]) : (ushort)0;
                        ushort e6 = (k0 + 6 < 49) ? f2bf(wc[o * 784 + k0 + 6]) : (ushort)0;
                        ushort e7 = (k0 + 7 < 49) ? f2bf(wc[o * 784 + k0 + 7]) : (ushort)0;
                        p0 = (uint)e0 | ((uint)e1 << 16);
                        p1 = (uint)e2 | ((uint)e3 << 16);
                        p2 = (uint)e4 | ((uint)e5 << 16);
                        p3 = (uint)e6 | ((uint)e7 << 16);
                        u.x = p0; u.y = p1; u.z = p2; u.w = p3;
                    }
                    afr[ob] = __builtin_bit_cast(short8v, u);
                }
                short8v bfr[4];
#pragma unroll
                for (int nb = 0; nb < 4; ++nb) {
                    const int p = wv * 64 + nb * 16 + olo;
                    uint4 u;
                    u.x = (uint)featB[p][k0 + 0] | ((uint)featB[p][k0 + 1] << 16);
                    u.y = (uint)featB[p][k0 + 2] | ((uint)featB[p][k0 + 3] << 16);
                    u.z = (uint)featB[p][k0 + 4] | ((uint)featB[p][k0 + 5] << 16);
                    u.w = (uint)featB[p][k0 + 6] | ((uint)featB[p][k0 + 7] << 16);
                    bfr[nb] = __builtin_bit_cast(short8v, u);
                }
#pragma unroll
                for (int ob = 0; ob < 4; ++ob)
#pragma unroll
                    for (int nb = 0; nb < 4; ++nb)
                        acc[ob][nb] = __builtin_amdgcn_mfma_f32_16x16x32_bf16(
                            afr[ob], bfr[nb], acc[ob][nb], 0, 0, 0);
            }
        }
        __syncthreads();
    }

    // ---- epilogue: D frag: col(pixel)=lane&15, row(o)=(lane>>4)*4+reg ----
#pragma unroll
    for (int ob = 0; ob < 4; ++ob)
#pragma unroll
        for (int nb = 0; nb < 4; ++nb) {
            const int p = wv * 64 + nb * 16 + (lane & 15);
            const int h = h0 + (p >> 5), w = w0 + (p & 31);
            const int o0 = ob * 16 + ((lane >> 4) << 2);
            float4v a = acc[ob][nb];
#pragma unroll
            for (int r = 0; r < 4; ++r) {
                const int o = o0 + r;
                out[(((size_t)b * Oo + o) * Hh + h) * Ww + w] = a[r] + bias[o];
            }
        }
}

} // namespace

extern "C" void kernel_launch(void* const* d_in, const int* in_sizes, int n_in,
                              void* d_out, int out_size, void* d_ws, size_t ws_size,
                              hipStream_t stream) {
    (void)in_sizes; (void)n_in; (void)d_ws; (void)ws_size; (void)out_size;
    const float* x    = (const float*)d_in[0];
    const float* wgt  = (const float*)d_in[1];
    const float* bias = (const float*)d_in[2];
    float* out        = (float*)d_out;

    dim3 grid(Ww / TW, Hh / TH, Bb);   // 6 x 48 x 4 = 1152 blocks
    dim3 block(NT);
    fova_v5<<<grid, block, 0, stream>>>(x, wgt, bias, out);
}

// Round 6
// 292.579 us; speedup vs baseline: 2.3866x; 1.0162x over previous
//
#include <hip/hip_runtime.h>

typedef __attribute__((ext_vector_type(8))) short short8v;   // bf16x8 fragment
typedef __attribute__((ext_vector_type(4))) float float4v;   // fp32x4 accum
typedef unsigned short ushort;
typedef unsigned int uint;

namespace {

constexpr int Hh = 192, Ww = 192, Cc = 16, Oo = 64, Bb = 4;
constexpr int TH = 4, TW = 32, NT = 128;     // 4x32 pixel tile, 128 threads (2 waves)

// Each feature = (vertical segment sum) + (horizontal segment sum), scaled by 1/n.
struct FD { int hasV; int vdj, vi0, vi1; int hasH; int hdi, hj0, hj1; float inv_n; };

constexpr FD FT[49] = {
    // 9 inner taps (i,j) row-major, n=1
    {1,-1,-1,-1, 0,0,0,0, 1.f}, {1, 0,-1,-1, 0,0,0,0, 1.f}, {1, 1,-1,-1, 0,0,0,0, 1.f},
    {1,-1, 0, 0, 0,0,0,0, 1.f}, {1, 0, 0, 0, 0,0,0,0, 1.f}, {1, 1, 0, 0, 0,0,0,0, 1.f},
    {1,-1, 1, 1, 0,0,0,0, 1.f}, {1, 0, 1, 1, 0,0,0,0, 1.f}, {1, 1, 1, 1, 0,0,0,0, 1.f},
    // ring5 (16)
    {1,-2,-2, 2, 1,-2,-1, 2, 1.f/9.f},
    {1,-1,-2, 2, 0,0,0,0, 0.2f},
    {1, 0,-2, 2, 0,0,0,0, 0.2f},
    {1, 1,-2, 2, 0,0,0,0, 0.2f},
    {1, 2,-2, 2, 1,-2,-2, 1, 1.f/9.f},
    {0,0,0,0, 1,-1,-2, 2, 0.2f},
    {0,0,0,0, 1,-1,-2, 2, 0.2f},
    {0,0,0,0, 1, 0,-2, 2, 0.2f},
    {0,0,0,0, 1, 0,-2, 2, 0.2f},
    {0,0,0,0, 1, 1,-2, 2, 0.2f},
    {0,0,0,0, 1, 1,-2, 2, 0.2f},
    {1,-2,-2, 2, 1, 2,-1, 2, 1.f/9.f},
    {1,-1,-2, 2, 0,0,0,0, 0.2f},
    {1, 0,-2, 2, 0,0,0,0, 0.2f},
    {1, 1,-2, 2, 0,0,0,0, 0.2f},
    {1, 2,-2, 2, 1, 2,-2, 1, 1.f/9.f},
    // ring7 (24)
    {1,-3,-3,11, 1,-3,-2,21, 1.f/39.f},
    {1,-2,-3,11, 0,0,0,0, 1.f/15.f},
    {1,-1,-3,11, 0,0,0,0, 1.f/15.f},
    {1, 0,-3,11, 0,0,0,0, 1.f/15.f},
    {1, 1,-3,11, 0,0,0,0, 1.f/15.f},
    {1, 2,-3,11, 0,0,0,0, 1.f/15.f},
    {1, 3,-3,11, 1,-3,-21, 2, 1.f/39.f},
    {0,0,0,0, 1,-2,-3,21, 0.04f},
    {0,0,0,0, 1,-2,-21,3, 0.04f},
    {0,0,0,0, 1,-1,-3,21, 0.04f},
    {0,0,0,0, 1,-1,-21,3, 0.04f},
    {0,0,0,0, 1, 0,-3,21, 0.04f},
    {0,0,0,0, 1, 0,-21,3, 0.04f},
    {0,0,0,0, 1, 1,-3,21, 0.04f},
    {0,0,0,0, 1, 1,-21,3, 0.04f},
    {0,0,0,0, 1, 2,-3,21, 0.04f},
    {0,0,0,0, 1, 2,-21,3, 0.04f},
    {1,-3,-11,3, 1, 3,-2,21, 1.f/39.f},
    {1,-2,-11,3, 0,0,0,0, 1.f/15.f},
    {1,-1,-11,3, 0,0,0,0, 1.f/15.f},
    {1, 0,-11,3, 0,0,0,0, 1.f/15.f},
    {1, 1,-11,3, 0,0,0,0, 1.f/15.f},
    {1, 2,-11,3, 0,0,0,0, 1.f/15.f},
    {1, 3,-11,3, 1, 3,-21,2, 1.f/39.f},
};

// reflect-pad(3) + clip index map; valid for u in [-21, 212]
__device__ __forceinline__ int mapIdx(int u) {
    if (u < 0) { u = -u; if (u > 3) u = 3; }
    else if (u > 191) { u = 382 - u; if (u < 188) u = 188; }
    return u;
}

__device__ __forceinline__ ushort f2bf(float f) {   // RNE fp32->bf16 bits
    uint u = __builtin_bit_cast(uint, f);
    u += 0x7FFFu + ((u >> 16) & 1u);
    return (ushort)(u >> 16);
}

__global__ __launch_bounds__(NT, 2)
void fova_v6(const float* __restrict__ x, const float* __restrict__ wgt,
             const float* __restrict__ bias, float* __restrict__ out)
{
    __shared__ float  E [26][76];      // extended x tile (R1-verbatim geometry)
    __shared__ float  PV[27][76];      // column prefixes, absolute cols 18..55 used
    __shared__ float  PH[26][76];      // row prefixes, absolute rows 8..17 used
    __shared__ ushort featB[NT][66];   // bf16 feat bits [pixel][k], padded stride (66)

    const int tid  = threadIdx.x;
    const int lane = tid & 63;
    const int wv   = tid >> 6;          // wave id 0/1
    const int w0   = blockIdx.x * TW;
    const int h0   = blockIdx.y * TH;
    const int b    = blockIdx.z;
    const int ph   = tid >> 5;          // pixel row 0..3 (tid == pixel id)
    const int pw   = tid & 31;
    const int ur   = ph + 11;           // pixel row in extended coords
    const int vcc  = pw + 21;           // pixel col in extended coords

    float4v acc[4][4];
#pragma unroll
    for (int i = 0; i < 4; ++i)
#pragma unroll
        for (int j = 0; j < 4; ++j) acc[i][j] = (float4v)(0.f);

    for (int c = 0; c < Cc; ++c) {
        // ---- phase 1: stage E(c) ----
        {
            const float* xp = x + (size_t)(b * Cc + c) * Hh * Ww;
            for (int idx = tid; idx < 26 * 74; idx += NT) {
                int uu = idx / 74, vvv = idx - uu * 74;
                E[uu][vvv] = xp[mapIdx(h0 + uu - 11) * Ww + mapIdx(w0 + vvv - 21)];
            }
        }
        __syncthreads();

        // ---- phase 2: serial prefix scans (PH now unrolled -> pipelined loads) ----
        if (tid < 38) {
            int col = 18 + tid;
            float r = 0.f;
            PV[0][col] = 0.f;
#pragma unroll
            for (int rr = 0; rr < 26; ++rr) { r += E[rr][col]; PV[rr + 1][col] = r; }
        }
        if (tid >= 96 && tid < 106) {
            int row = 8 + (tid - 96);
            float r = 0.f;
            PH[row][0] = 0.f;
#pragma unroll
            for (int s = 0; s < 74; ++s) { r += E[row][s]; PH[row][s + 1] = r; }
        }
        __syncthreads();

        // ---- phase 3: features -> scalar bf16 stores ----
        {
            float feat[49];
#pragma unroll
            for (int f = 0; f < 49; ++f) {
                float s = 0.f;
                if (FT[f].hasV) {
                    int col = vcc + FT[f].vdj;
                    s += PV[ur + FT[f].vi1 + 1][col] - PV[ur + FT[f].vi0][col];
                }
                if (FT[f].hasH) {
                    int row = ur + FT[f].hdi;
                    s += PH[row][vcc + FT[f].hj1 + 1] - PH[row][vcc + FT[f].hj0];
                }
                feat[f] = s * FT[f].inv_n;
            }
#pragma unroll
            for (int f = 0; f < 49; ++f) featB[tid][f] = f2bf(feat[f]);
#pragma unroll
            for (int f = 49; f < 64; ++f) featB[tid][f] = 0;
        }
        __syncthreads();

        // ---- phase 4: contraction via MFMA ----
        {
            const float* wc = wgt + c * 49;
            const int olo = lane & 15, kg = lane >> 4;
#pragma unroll
            for (int kc = 0; kc < 2; ++kc) {
                const int k0 = kc * 32 + kg * 8;
                short8v afr[4];
#pragma unroll
                for (int ob = 0; ob < 4; ++ob) {
                    const int o = ob * 16 + olo;
                    uint4 u;
                    {
                        ushort e0 = (k0 + 0 < 49) ? f2bf(wc[o * 784 + k0 + 0]) : (ushort)0;
                        ushort e1 = (k0 + 1 < 49) ? f2bf(wc[o * 784 + k0 + 1]) : (ushort)0;
                        ushort e2 = (k0 + 2 < 49) ? f2bf(wc[o * 784 + k0 + 2]) : (ushort)0;
                        ushort e3 = (k0 + 3 < 49) ? f2bf(wc[o * 784 + k0 + 3]) : (ushort)0;
                        ushort e4 = (k0 + 4 < 49) ? f2bf(wc[o * 784 + k0 + 4]) : (ushort)0;
                        ushort e5 = (k0 + 5 < 49) ? f2bf(wc[o * 784 + k0 + 5]) : (ushort)0;
                        ushort e6 = (k0 + 6 < 49) ? f2bf(wc[o * 784 + k0 + 6]) : (ushort)0;
                        ushort e7 = (k0 + 7 < 49) ? f2bf(wc[o * 784 + k0 + 7]) : (ushort)0;
                        u.x = (uint)e0 | ((uint)e1 << 16);
                        u.y = (uint)e2 | ((uint)e3 << 16);
                        u.z = (uint)e4 | ((uint)e5 << 16);
                        u.w = (uint)e6 | ((uint)e7 << 16);
                    }
                    afr[ob] = __builtin_bit_cast(short8v, u);
                }
                short8v bfr[4];
#pragma unroll
                for (int nb = 0; nb < 4; ++nb) {
                    const int p = wv * 64 + nb * 16 + olo;
                    // 4B-aligned uint reads: (p*66 + k0)*2 % 4 == 0 (k0 even)
                    const uint* bp = (const uint*)(&featB[p][k0]);
                    uint4 u;
                    u.x = bp[0]; u.y = bp[1]; u.z = bp[2]; u.w = bp[3];
                    bfr[nb] = __builtin_bit_cast(short8v, u);
                }
#pragma unroll
                for (int ob = 0; ob < 4; ++ob)
#pragma unroll
                    for (int nb = 0; nb < 4; ++nb)
                        acc[ob][nb] = __builtin_amdgcn_mfma_f32_16x16x32_bf16(
                            afr[ob], bfr[nb], acc[ob][nb], 0, 0, 0);
            }
        }
        __syncthreads();
    }

    // ---- epilogue: D frag: col(pixel)=lane&15, row(o)=(lane>>4)*4+reg ----
#pragma unroll
    for (int ob = 0; ob < 4; ++ob)
#pragma unroll
        for (int nb = 0; nb < 4; ++nb) {
            const int p = wv * 64 + nb * 16 + (lane & 15);
            const int h = h0 + (p >> 5), w = w0 + (p & 31);
            const int o0 = ob * 16 + ((lane >> 4) << 2);
            float4v a = acc[ob][nb];
#pragma unroll
            for (int r = 0; r < 4; ++r) {
                const int o = o0 + r;
                out[(((size_t)b * Oo + o) * Hh + h) * Ww + w] = a[r] + bias[o];
            }
        }
}

} // namespace

extern "C" void kernel_launch(void* const* d_in, const int* in_sizes, int n_in,
                              void* d_out, int out_size, void* d_ws, size_t ws_size,
                              hipStream_t stream) {
    (void)in_sizes; (void)n_in; (void)d_ws; (void)ws_size; (void)out_size;
    const float* x    = (const float*)d_in[0];
    const float* wgt  = (const float*)d_in[1];
    const float* bias = (const float*)d_in[2];
    float* out        = (float*)d_out;

    dim3 grid(Ww / TW, Hh / TH, Bb);   // 6 x 48 x 4 = 1152 blocks
    dim3 block(NT);
    fova_v6<<<grid, block, 0, stream>>>(x, wgt, bias, out);
}

// Round 7
// 238.516 us; speedup vs baseline: 2.9276x; 1.2267x over previous
//
#include <hip/hip_runtime.h>

typedef __attribute__((ext_vector_type(8))) short short8v;   // bf16x8 fragment
typedef __attribute__((ext_vector_type(4))) float float4v;   // fp32x4 accum
typedef unsigned short ushort;
typedef unsigned int uint;

namespace {

constexpr int Hh = 192, Ww = 192, Cc = 16, Oo = 64, Bb = 4;
constexpr int TH = 4, TW = 32, NT = 128;     // 4x32 pixel tile, 128 threads (2 waves)

// Each feature = (vertical segment sum) + (horizontal segment sum), scaled by 1/n.
struct FD { int hasV; int vdj, vi0, vi1; int hasH; int hdi, hj0, hj1; float inv_n; };

constexpr FD FT[49] = {
    // 9 inner taps (i,j) row-major, n=1
    {1,-1,-1,-1, 0,0,0,0, 1.f}, {1, 0,-1,-1, 0,0,0,0, 1.f}, {1, 1,-1,-1, 0,0,0,0, 1.f},
    {1,-1, 0, 0, 0,0,0,0, 1.f}, {1, 0, 0, 0, 0,0,0,0, 1.f}, {1, 1, 0, 0, 0,0,0,0, 1.f},
    {1,-1, 1, 1, 0,0,0,0, 1.f}, {1, 0, 1, 1, 0,0,0,0, 1.f}, {1, 1, 1, 1, 0,0,0,0, 1.f},
    // ring5 (16)
    {1,-2,-2, 2, 1,-2,-1, 2, 1.f/9.f},
    {1,-1,-2, 2, 0,0,0,0, 0.2f},
    {1, 0,-2, 2, 0,0,0,0, 0.2f},
    {1, 1,-2, 2, 0,0,0,0, 0.2f},
    {1, 2,-2, 2, 1,-2,-2, 1, 1.f/9.f},
    {0,0,0,0, 1,-1,-2, 2, 0.2f},
    {0,0,0,0, 1,-1,-2, 2, 0.2f},
    {0,0,0,0, 1, 0,-2, 2, 0.2f},
    {0,0,0,0, 1, 0,-2, 2, 0.2f},
    {0,0,0,0, 1, 1,-2, 2, 0.2f},
    {0,0,0,0, 1, 1,-2, 2, 0.2f},
    {1,-2,-2, 2, 1, 2,-1, 2, 1.f/9.f},
    {1,-1,-2, 2, 0,0,0,0, 0.2f},
    {1, 0,-2, 2, 0,0,0,0, 0.2f},
    {1, 1,-2, 2, 0,0,0,0, 0.2f},
    {1, 2,-2, 2, 1, 2,-2, 1, 1.f/9.f},
    // ring7 (24)
    {1,-3,-3,11, 1,-3,-2,21, 1.f/39.f},
    {1,-2,-3,11, 0,0,0,0, 1.f/15.f},
    {1,-1,-3,11, 0,0,0,0, 1.f/15.f},
    {1, 0,-3,11, 0,0,0,0, 1.f/15.f},
    {1, 1,-3,11, 0,0,0,0, 1.f/15.f},
    {1, 2,-3,11, 0,0,0,0, 1.f/15.f},
    {1, 3,-3,11, 1,-3,-21, 2, 1.f/39.f},
    {0,0,0,0, 1,-2,-3,21, 0.04f},
    {0,0,0,0, 1,-2,-21,3, 0.04f},
    {0,0,0,0, 1,-1,-3,21, 0.04f},
    {0,0,0,0, 1,-1,-21,3, 0.04f},
    {0,0,0,0, 1, 0,-3,21, 0.04f},
    {0,0,0,0, 1, 0,-21,3, 0.04f},
    {0,0,0,0, 1, 1,-3,21, 0.04f},
    {0,0,0,0, 1, 1,-21,3, 0.04f},
    {0,0,0,0, 1, 2,-3,21, 0.04f},
    {0,0,0,0, 1, 2,-21,3, 0.04f},
    {1,-3,-11,3, 1, 3,-2,21, 1.f/39.f},
    {1,-2,-11,3, 0,0,0,0, 1.f/15.f},
    {1,-1,-11,3, 0,0,0,0, 1.f/15.f},
    {1, 0,-11,3, 0,0,0,0, 1.f/15.f},
    {1, 1,-11,3, 0,0,0,0, 1.f/15.f},
    {1, 2,-11,3, 0,0,0,0, 1.f/15.f},
    {1, 3,-11,3, 1, 3,-21,2, 1.f/39.f},
};

// reflect-pad(3) + clip index map; valid for u in [-21, 212]
__device__ __forceinline__ int mapIdx(int u) {
    if (u < 0) { u = -u; if (u > 3) u = 3; }
    else if (u > 191) { u = 382 - u; if (u < 188) u = 188; }
    return u;
}

__device__ __forceinline__ ushort f2bf(float f) {   // RNE fp32->bf16 bits
    uint u = __builtin_bit_cast(uint, f);
    u += 0x7FFFu + ((u >> 16) & 1u);
    return (ushort)(u >> 16);
}

__global__ __launch_bounds__(NT, 2)
void fova_v7(const float* __restrict__ x, const float* __restrict__ wgt,
             const float* __restrict__ bias, float* __restrict__ out)
{
    __shared__ float  E   [26][76];    // extended x tile (proven geometry)
    __shared__ float  PVt [27][40];    // column prefixes, cols (abs 18..55) -> [0..37]
    __shared__ float  PHt [10][76];    // row prefixes, rows (abs 8..17) -> [0..9]
    __shared__ ushort featB[NT][66];   // bf16 feat bits [pixel][k], padded stride
    __shared__ ushort wlds [64][66];   // bf16 weight slice [o][k], padded stride

    const int tid  = threadIdx.x;
    const int lane = tid & 63;
    const int wv   = tid >> 6;          // wave id 0/1
    const int w0   = blockIdx.x * TW;
    const int h0   = blockIdx.y * TH;
    const int b    = blockIdx.z;
    const int ph   = tid >> 5;          // pixel row 0..3 (tid == pixel id)
    const int pw   = tid & 31;
    const int ur   = ph + 11;           // pixel row in extended coords
    const int vcc  = pw + 21;           // pixel col in extended coords

    float4v acc[4][4];
#pragma unroll
    for (int i = 0; i < 4; ++i)
#pragma unroll
        for (int j = 0; j < 4; ++j) acc[i][j] = (float4v)(0.f);

    // one-time: zero weight pad slots k=49..63 (never rewritten)
    if (tid < 64) {
#pragma unroll
        for (int f = 49; f < 64; ++f) wlds[tid][f] = 0;
    }

    for (int c = 0; c < Cc; ++c) {
        // ---- phase 1: stage E(c) + stage W(c) into LDS ----
        {
            const float* xp = x + (size_t)(b * Cc + c) * Hh * Ww;
            for (int idx = tid; idx < 26 * 74; idx += NT) {
                int uu = idx / 74, vvv = idx - uu * 74;
                E[uu][vvv] = xp[mapIdx(h0 + uu - 11) * Ww + mapIdx(w0 + vvv - 21)];
            }
            const float* wc = wgt + c * 49;
            for (int idx = tid; idx < 64 * 49; idx += NT) {
                int o = idx / 49, f = idx - o * 49;
                wlds[o][f] = f2bf(wc[o * 784 + f]);
            }
        }
        __syncthreads();

        // ---- phase 2: serial prefix scans ----
        if (tid < 38) {
            int cv = tid;                 // abs col 18+tid
            float r = 0.f;
            PVt[0][cv] = 0.f;
#pragma unroll
            for (int rr = 0; rr < 26; ++rr) { r += E[rr][18 + cv]; PVt[rr + 1][cv] = r; }
        }
        if (tid >= 96 && tid < 106) {
            int rv = tid - 96;            // abs row 8+rv
            float r = 0.f;
            PHt[rv][0] = 0.f;
#pragma unroll
            for (int s = 0; s < 74; ++s) { r += E[8 + rv][s]; PHt[rv][s + 1] = r; }
        }
        __syncthreads();

        // ---- phase 3: features -> scalar bf16 stores ----
        {
            float feat[49];
#pragma unroll
            for (int f = 0; f < 49; ++f) {
                float s = 0.f;
                if (FT[f].hasV) {
                    int cv = pw + 3 + FT[f].vdj;          // abs col - 18
                    s += PVt[ur + FT[f].vi1 + 1][cv] - PVt[ur + FT[f].vi0][cv];
                }
                if (FT[f].hasH) {
                    int rv = ph + 3 + FT[f].hdi;          // abs row - 8
                    s += PHt[rv][vcc + FT[f].hj1 + 1] - PHt[rv][vcc + FT[f].hj0];
                }
                feat[f] = s * FT[f].inv_n;
            }
#pragma unroll
            for (int f = 0; f < 49; ++f) featB[tid][f] = f2bf(feat[f]);
#pragma unroll
            for (int f = 49; f < 64; ++f) featB[tid][f] = 0;
        }
        __syncthreads();

        // ---- phase 4: contraction via MFMA (A from wlds, B from featB) ----
        {
            const int olo = lane & 15, kg = lane >> 4;
#pragma unroll
            for (int kc = 0; kc < 2; ++kc) {
                const int k0 = kc * 32 + kg * 8;          // even -> 4B aligned
                short8v afr[4];
#pragma unroll
                for (int ob = 0; ob < 4; ++ob) {
                    const int o = ob * 16 + olo;
                    const uint* wp = (const uint*)(&wlds[o][k0]);
                    uint4 u;
                    u.x = wp[0]; u.y = wp[1]; u.z = wp[2]; u.w = wp[3];
                    afr[ob] = __builtin_bit_cast(short8v, u);
                }
                short8v bfr[4];
#pragma unroll
                for (int nb = 0; nb < 4; ++nb) {
                    const int p = wv * 64 + nb * 16 + olo;
                    const uint* bp = (const uint*)(&featB[p][k0]);
                    uint4 u;
                    u.x = bp[0]; u.y = bp[1]; u.z = bp[2]; u.w = bp[3];
                    bfr[nb] = __builtin_bit_cast(short8v, u);
                }
#pragma unroll
                for (int ob = 0; ob < 4; ++ob)
#pragma unroll
                    for (int nb = 0; nb < 4; ++nb)
                        acc[ob][nb] = __builtin_amdgcn_mfma_f32_16x16x32_bf16(
                            afr[ob], bfr[nb], acc[ob][nb], 0, 0, 0);
            }
        }
        __syncthreads();
    }

    // ---- epilogue: D frag: col(pixel)=lane&15, row(o)=(lane>>4)*4+reg ----
#pragma unroll
    for (int ob = 0; ob < 4; ++ob)
#pragma unroll
        for (int nb = 0; nb < 4; ++nb) {
            const int p = wv * 64 + nb * 16 + (lane & 15);
            const int h = h0 + (p >> 5), w = w0 + (p & 31);
            const int o0 = ob * 16 + ((lane >> 4) << 2);
            float4v a = acc[ob][nb];
#pragma unroll
            for (int r = 0; r < 4; ++r) {
                const int o = o0 + r;
                out[(((size_t)b * Oo + o) * Hh + h) * Ww + w] = a[r] + bias[o];
            }
        }
}

} // namespace

extern "C" void kernel_launch(void* const* d_in, const int* in_sizes, int n_in,
                              void* d_out, int out_size, void* d_ws, size_t ws_size,
                              hipStream_t stream) {
    (void)in_sizes; (void)n_in; (void)d_ws; (void)ws_size; (void)out_size;
    const float* x    = (const float*)d_in[0];
    const float* wgt  = (const float*)d_in[1];
    const float* bias = (const float*)d_in[2];
    float* out        = (float*)d_out;

    dim3 grid(Ww / TW, Hh / TH, Bb);   // 6 x 48 x 4 = 1152 blocks
    dim3 block(NT);
    fova_v7<<<grid, block, 0, stream>>>(x, wgt, bias, out);
}

// Round 8
// 188.654 us; speedup vs baseline: 3.7013x; 1.2643x over previous
//
#include <hip/hip_runtime.h>

typedef __attribute__((ext_vector_type(8))) short short8v;   // bf16x8 fragment
typedef __attribute__((ext_vector_type(4))) float float4v;   // fp32x4 accum
typedef unsigned short ushort;
typedef unsigned int uint;

namespace {

constexpr int Hh = 192, Ww = 192, Cc = 16, Oo = 64, Bb = 4;
constexpr int TH = 4, TW = 32, NT = 128;     // 4x32 pixel tile, 128 threads (2 waves)

// Each feature = (vertical segment sum) + (horizontal segment sum), scaled by 1/n.
struct FD { int hasV; int vdj, vi0, vi1; int hasH; int hdi, hj0, hj1; float inv_n; };

constexpr FD FT[49] = {
    // 9 inner taps (i,j) row-major, n=1
    {1,-1,-1,-1, 0,0,0,0, 1.f}, {1, 0,-1,-1, 0,0,0,0, 1.f}, {1, 1,-1,-1, 0,0,0,0, 1.f},
    {1,-1, 0, 0, 0,0,0,0, 1.f}, {1, 0, 0, 0, 0,0,0,0, 1.f}, {1, 1, 0, 0, 0,0,0,0, 1.f},
    {1,-1, 1, 1, 0,0,0,0, 1.f}, {1, 0, 1, 1, 0,0,0,0, 1.f}, {1, 1, 1, 1, 0,0,0,0, 1.f},
    // ring5 (16)
    {1,-2,-2, 2, 1,-2,-1, 2, 1.f/9.f},
    {1,-1,-2, 2, 0,0,0,0, 0.2f},
    {1, 0,-2, 2, 0,0,0,0, 0.2f},
    {1, 1,-2, 2, 0,0,0,0, 0.2f},
    {1, 2,-2, 2, 1,-2,-2, 1, 1.f/9.f},
    {0,0,0,0, 1,-1,-2, 2, 0.2f},
    {0,0,0,0, 1,-1,-2, 2, 0.2f},
    {0,0,0,0, 1, 0,-2, 2, 0.2f},
    {0,0,0,0, 1, 0,-2, 2, 0.2f},
    {0,0,0,0, 1, 1,-2, 2, 0.2f},
    {0,0,0,0, 1, 1,-2, 2, 0.2f},
    {1,-2,-2, 2, 1, 2,-1, 2, 1.f/9.f},
    {1,-1,-2, 2, 0,0,0,0, 0.2f},
    {1, 0,-2, 2, 0,0,0,0, 0.2f},
    {1, 1,-2, 2, 0,0,0,0, 0.2f},
    {1, 2,-2, 2, 1, 2,-2, 1, 1.f/9.f},
    // ring7 (24)
    {1,-3,-3,11, 1,-3,-2,21, 1.f/39.f},
    {1,-2,-3,11, 0,0,0,0, 1.f/15.f},
    {1,-1,-3,11, 0,0,0,0, 1.f/15.f},
    {1, 0,-3,11, 0,0,0,0, 1.f/15.f},
    {1, 1,-3,11, 0,0,0,0, 1.f/15.f},
    {1, 2,-3,11, 0,0,0,0, 1.f/15.f},
    {1, 3,-3,11, 1,-3,-21, 2, 1.f/39.f},
    {0,0,0,0, 1,-2,-3,21, 0.04f},
    {0,0,0,0, 1,-2,-21,3, 0.04f},
    {0,0,0,0, 1,-1,-3,21, 0.04f},
    {0,0,0,0, 1,-1,-21,3, 0.04f},
    {0,0,0,0, 1, 0,-3,21, 0.04f},
    {0,0,0,0, 1, 0,-21,3, 0.04f},
    {0,0,0,0, 1, 1,-3,21, 0.04f},
    {0,0,0,0, 1, 1,-21,3, 0.04f},
    {0,0,0,0, 1, 2,-3,21, 0.04f},
    {0,0,0,0, 1, 2,-21,3, 0.04f},
    {1,-3,-11,3, 1, 3,-2,21, 1.f/39.f},
    {1,-2,-11,3, 0,0,0,0, 1.f/15.f},
    {1,-1,-11,3, 0,0,0,0, 1.f/15.f},
    {1, 0,-11,3, 0,0,0,0, 1.f/15.f},
    {1, 1,-11,3, 0,0,0,0, 1.f/15.f},
    {1, 2,-11,3, 0,0,0,0, 1.f/15.f},
    {1, 3,-11,3, 1, 3,-21,2, 1.f/39.f},
};

// reflect-pad(3) + clip index map; valid for u in [-21, 212]
__device__ __forceinline__ int mapIdx(int u) {
    if (u < 0) { u = -u; if (u > 3) u = 3; }
    else if (u > 191) { u = 382 - u; if (u < 188) u = 188; }
    return u;
}

__device__ __forceinline__ ushort f2bf(float f) {   // RNE fp32->bf16 bits
    uint u = __builtin_bit_cast(uint, f);
    u += 0x7FFFu + ((u >> 16) & 1u);
    return (ushort)(u >> 16);
}

// LDS layout (bytes): union { E[26][76]f (7904) | PVt[27][40]f (+4320) | PHt[10][76]f (+3040) = 15264 }
//                     aliased with featB[128][66]u16 (16896)  -> region size 16896
// wlds[64][72]u16 (9216) separate.  Total 26112 B -> 6 blocks/CU.
constexpr int OFF_PVT = 26 * 76 * 4;              // 7904
constexpr int OFF_PHT = OFF_PVT + 27 * 40 * 4;    // 12224
constexpr int SM_BYTES = 128 * 66 * 2;            // 16896 (featB is the largest)

__global__ __launch_bounds__(NT, 3)
void fova_v8(const float* __restrict__ x, const float* __restrict__ wgt,
             const float* __restrict__ bias, float* __restrict__ out)
{
    __shared__ __align__(16) char smraw[SM_BYTES];
    __shared__ ushort wlds[64][72];    // bf16 weight slice [o][k], 144B rows (16B-aligned)

    float (*E)[76]      = reinterpret_cast<float(*)[76]>(smraw);
    float (*PVt)[40]    = reinterpret_cast<float(*)[40]>(smraw + OFF_PVT);
    float (*PHt)[76]    = reinterpret_cast<float(*)[76]>(smraw + OFF_PHT);
    ushort (*featB)[66] = reinterpret_cast<ushort(*)[66]>(smraw);

    const int tid  = threadIdx.x;
    const int lane = tid & 63;
    const int wv   = tid >> 6;          // wave id 0/1
    const int w0   = blockIdx.x * TW;
    const int h0   = blockIdx.y * TH;
    const int b    = blockIdx.z;
    const int ph   = tid >> 5;          // pixel row 0..3 (tid == pixel id)
    const int pw   = tid & 31;
    const int ur   = ph + 11;           // pixel row in extended coords
    const int vcc  = pw + 21;           // pixel col in extended coords

    float4v acc[4][4];
#pragma unroll
    for (int i = 0; i < 4; ++i)
#pragma unroll
        for (int j = 0; j < 4; ++j) acc[i][j] = (float4v)(0.f);

    // one-time: zero weight pad slots k=49..63 (never rewritten)
    if (tid < 64) {
#pragma unroll
        for (int f = 49; f < 64; ++f) wlds[tid][f] = 0;
    }

    for (int c = 0; c < Cc; ++c) {
        // ---- phase 1: stage E(c) + stage W(c) into LDS ----
        {
            const float* xp = x + (size_t)(b * Cc + c) * Hh * Ww;
            for (int idx = tid; idx < 26 * 74; idx += NT) {
                int uu = idx / 74, vvv = idx - uu * 74;
                E[uu][vvv] = xp[mapIdx(h0 + uu - 11) * Ww + mapIdx(w0 + vvv - 21)];
            }
            const float* wc = wgt + c * 49;
            for (int idx = tid; idx < 64 * 49; idx += NT) {
                int o = idx / 49, f = idx - o * 49;
                wlds[o][f] = f2bf(wc[o * 784 + f]);
            }
        }
        __syncthreads();

        // ---- phase 2: serial prefix scans ----
        if (tid < 38) {
            int cv = tid;                 // abs col 18+tid
            float r = 0.f;
            PVt[0][cv] = 0.f;
#pragma unroll
            for (int rr = 0; rr < 26; ++rr) { r += E[rr][18 + cv]; PVt[rr + 1][cv] = r; }
        }
        if (tid >= 96 && tid < 106) {
            int rv = tid - 96;            // abs row 8+rv
            float r = 0.f;
            PHt[rv][0] = 0.f;
#pragma unroll
            for (int s = 0; s < 74; ++s) { r += E[8 + rv][s]; PHt[rv][s + 1] = r; }
        }
        __syncthreads();

        // ---- phase 3a: features into registers ----
        float feat[49];
        {
#pragma unroll
            for (int f = 0; f < 49; ++f) {
                float s = 0.f;
                if (FT[f].hasV) {
                    int cv = pw + 3 + FT[f].vdj;          // abs col - 18
                    s += PVt[ur + FT[f].vi1 + 1][cv] - PVt[ur + FT[f].vi0][cv];
                }
                if (FT[f].hasH) {
                    int rv = ph + 3 + FT[f].hdi;          // abs row - 8
                    s += PHt[rv][vcc + FT[f].hj1 + 1] - PHt[rv][vcc + FT[f].hj0];
                }
                feat[f] = s * FT[f].inv_n;
            }
        }
        __syncthreads();   // all E/PVt/PHt reads complete before featB overwrites them

        // ---- phase 3b: write featB (aliases E/PVt/PHt region) ----
        {
#pragma unroll
            for (int f = 0; f < 49; ++f) featB[tid][f] = f2bf(feat[f]);
#pragma unroll
            for (int f = 49; f < 64; ++f) featB[tid][f] = 0;
        }
        __syncthreads();

        // ---- phase 4: contraction via MFMA (A from wlds b128, B from featB) ----
        {
            const int olo = lane & 15, kg = lane >> 4;
#pragma unroll
            for (int kc = 0; kc < 2; ++kc) {
                const int k0 = kc * 32 + kg * 8;          // multiple of 8 -> 16B aligned in wlds
                short8v afr[4];
#pragma unroll
                for (int ob = 0; ob < 4; ++ob) {
                    const int o = ob * 16 + olo;
                    afr[ob] = *(const short8v*)(&wlds[o][k0]);
                }
                short8v bfr[4];
#pragma unroll
                for (int nb = 0; nb < 4; ++nb) {
                    const int p = wv * 64 + nb * 16 + olo;
                    const uint* bp = (const uint*)(&featB[p][k0]);
                    uint4 u;
                    u.x = bp[0]; u.y = bp[1]; u.z = bp[2]; u.w = bp[3];
                    bfr[nb] = __builtin_bit_cast(short8v, u);
                }
#pragma unroll
                for (int ob = 0; ob < 4; ++ob)
#pragma unroll
                    for (int nb = 0; nb < 4; ++nb)
                        acc[ob][nb] = __builtin_amdgcn_mfma_f32_16x16x32_bf16(
                            afr[ob], bfr[nb], acc[ob][nb], 0, 0, 0);
            }
        }
        __syncthreads();   // featB (aliased with E) must be fully read before next stage
    }

    // ---- epilogue: D frag: col(pixel)=lane&15, row(o)=(lane>>4)*4+reg ----
#pragma unroll
    for (int ob = 0; ob < 4; ++ob)
#pragma unroll
        for (int nb = 0; nb < 4; ++nb) {
            const int p = wv * 64 + nb * 16 + (lane & 15);
            const int h = h0 + (p >> 5), w = w0 + (p & 31);
            const int o0 = ob * 16 + ((lane >> 4) << 2);
            float4v a = acc[ob][nb];
#pragma unroll
            for (int r = 0; r < 4; ++r) {
                const int o = o0 + r;
                out[(((size_t)b * Oo + o) * Hh + h) * Ww + w] = a[r] + bias[o];
            }
        }
}

} // namespace

extern "C" void kernel_launch(void* const* d_in, const int* in_sizes, int n_in,
                              void* d_out, int out_size, void* d_ws, size_t ws_size,
                              hipStream_t stream) {
    (void)in_sizes; (void)n_in; (void)d_ws; (void)ws_size; (void)out_size;
    const float* x    = (const float*)d_in[0];
    const float* wgt  = (const float*)d_in[1];
    const float* bias = (const float*)d_in[2];
    float* out        = (float*)d_out;

    dim3 grid(Ww / TW, Hh / TH, Bb);   // 6 x 48 x 4 = 1152 blocks
    dim3 block(NT);
    fova_v8<<<grid, block, 0, stream>>>(x, wgt, bias, out);
}